// Round 1
// baseline (366.328 us; speedup 1.0000x reference)
//
#include <hip/hip_runtime.h>
#include <math.h>

// LIF forward: x[B,T,N], thresh[N], tau_x[N] -> spikes[B,T,N], mems[B,T,N]
// Recurrence per (b,n): mem = (x - mem)*sig + mem; spike = mem>=thresh; mem = spike?0:mem
// Memory-bound: 384 MiB total traffic -> ~64us floor at 6.3 TB/s.

constexpr int B = 32;
constexpr int T = 64;
constexpr int N = 16384;
constexpr int N4 = N / 4;

__global__ __launch_bounds__(256) void lif_fwd_kernel(
    const float4* __restrict__ x,       // [B, T, N4]
    const float4* __restrict__ thresh,  // [N4]
    const float4* __restrict__ tau_x,   // [N4]
    float4* __restrict__ spikes,        // [B, T, N4]
    float4* __restrict__ mems)          // [B, T, N4]
{
    const int g = blockIdx.x * blockDim.x + threadIdx.x;
    if (g >= B * N4) return;
    const int n4 = g & (N4 - 1);   // N4 = 4096, power of two
    const int b  = g >> 12;        // g / N4

    const float4 th = thresh[n4];
    const float4 tx = tau_x[n4];

    // sigmoid in double for max fidelity to the high-precision reference
    const double sig0 = 1.0 / (1.0 + exp(-(double)tx.x));
    const double sig1 = 1.0 / (1.0 + exp(-(double)tx.y));
    const double sig2 = 1.0 / (1.0 + exp(-(double)tx.z));
    const double sig3 = 1.0 / (1.0 + exp(-(double)tx.w));
    const double th0 = (double)th.x, th1 = (double)th.y,
                 th2 = (double)th.z, th3 = (double)th.w;

    double m0 = 0.0, m1 = 0.0, m2 = 0.0, m3 = 0.0;

    const long base = (long)b * T * N4 + n4;

#pragma unroll 4
    for (int t = 0; t < T; ++t) {
        const long idx = base + (long)t * N4;
        const float4 xv = x[idx];

        m0 = ((double)xv.x - m0) * sig0 + m0;
        m1 = ((double)xv.y - m1) * sig1 + m1;
        m2 = ((double)xv.z - m2) * sig2 + m2;
        m3 = ((double)xv.w - m3) * sig3 + m3;

        const float s0 = (m0 >= th0) ? 1.0f : 0.0f;
        const float s1 = (m1 >= th1) ? 1.0f : 0.0f;
        const float s2 = (m2 >= th2) ? 1.0f : 0.0f;
        const float s3 = (m3 >= th3) ? 1.0f : 0.0f;

        if (s0 != 0.0f) m0 = 0.0;
        if (s1 != 0.0f) m1 = 0.0;
        if (s2 != 0.0f) m2 = 0.0;
        if (s3 != 0.0f) m3 = 0.0;

        spikes[idx] = make_float4(s0, s1, s2, s3);
        mems[idx]   = make_float4((float)m0, (float)m1, (float)m2, (float)m3);
    }
}

extern "C" void kernel_launch(void* const* d_in, const int* in_sizes, int n_in,
                              void* d_out, int out_size, void* d_ws, size_t ws_size,
                              hipStream_t stream) {
    const float4* x      = (const float4*)d_in[0];
    const float4* thresh = (const float4*)d_in[1];
    const float4* tau_x  = (const float4*)d_in[2];

    float* out = (float*)d_out;
    float4* spikes = (float4*)out;                       // first B*T*N floats
    float4* mems   = (float4*)(out + (size_t)B * T * N); // second B*T*N floats

    const int total_threads = B * N4;  // 131072
    const int block = 256;
    const int grid = (total_threads + block - 1) / block;  // 512

    lif_fwd_kernel<<<grid, block, 0, stream>>>(x, thresh, tau_x, spikes, mems);
}